// Round 1
// baseline (696.338 us; speedup 1.0000x reference)
//
#include <hip/hip_runtime.h>
#include <cstdint>
#include <cstddef>

#define TPB 256

// ---------------- CSR build ----------------

__global__ __launch_bounds__(TPB) void k_zero(int* __restrict__ counts, int* __restrict__ cursor, int n) {
    int i = blockIdx.x * blockDim.x + threadIdx.x;
    int stride = gridDim.x * blockDim.x;
    for (; i <= n; i += stride) {
        counts[i] = 0;
        if (i < n) cursor[i] = 0;
    }
}

__global__ __launch_bounds__(TPB) void k_count(const int* __restrict__ dst, int* __restrict__ counts, int E) {
    int i = blockIdx.x * blockDim.x + threadIdx.x;
    int stride = gridDim.x * blockDim.x;
    for (; i < E; i += stride) atomicAdd(&counts[dst[i]], 1);
}

__global__ __launch_bounds__(TPB) void k_scan1(const int* __restrict__ counts, int* __restrict__ bsum, int total) {
    __shared__ int sh[TPB];
    int base = blockIdx.x * 1024;
    int s = 0;
#pragma unroll
    for (int j = 0; j < 4; ++j) {
        int idx = base + threadIdx.x * 4 + j;
        if (idx < total) s += counts[idx];
    }
    sh[threadIdx.x] = s;
    __syncthreads();
    for (int off = 128; off > 0; off >>= 1) {
        if (threadIdx.x < off) sh[threadIdx.x] += sh[threadIdx.x + off];
        __syncthreads();
    }
    if (threadIdx.x == 0) bsum[blockIdx.x] = sh[0];
}

__global__ void k_scan2(int* __restrict__ bsum, int nb) {
    __shared__ int sh[128];
    int t = threadIdx.x;
    int v = (t < nb) ? bsum[t] : 0;
    sh[t] = v;
    __syncthreads();
    for (int off = 1; off < 128; off <<= 1) {
        int u = 0;
        if (t >= off) u = sh[t - off];
        __syncthreads();
        sh[t] += u;
        __syncthreads();
    }
    if (t < nb) bsum[t] = sh[t] - v;  // exclusive
}

__global__ __launch_bounds__(TPB) void k_scan3(const int* __restrict__ counts, const int* __restrict__ bsum,
                                               int* __restrict__ offs, int total) {
    __shared__ int sh[TPB];
    int base = blockIdx.x * 1024;
    int v[4];
    int s = 0;
#pragma unroll
    for (int j = 0; j < 4; ++j) {
        int idx = base + threadIdx.x * 4 + j;
        v[j] = (idx < total) ? counts[idx] : 0;
        s += v[j];
    }
    sh[threadIdx.x] = s;
    __syncthreads();
    for (int off = 1; off < TPB; off <<= 1) {
        int t = 0;
        if (threadIdx.x >= off) t = sh[threadIdx.x - off];
        __syncthreads();
        sh[threadIdx.x] += t;
        __syncthreads();
    }
    int pre = bsum[blockIdx.x] + sh[threadIdx.x] - s;  // exclusive prefix for this thread
#pragma unroll
    for (int j = 0; j < 4; ++j) {
        int idx = base + threadIdx.x * 4 + j;
        if (idx < total) { offs[idx] = pre; pre += v[j]; }
    }
}

__global__ __launch_bounds__(TPB) void k_scatter(const int* __restrict__ src, const int* __restrict__ dst,
                                                 const int* __restrict__ offs, int* __restrict__ cursor,
                                                 int* __restrict__ csr_src, int E) {
    int i = blockIdx.x * blockDim.x + threadIdx.x;
    int stride = gridDim.x * blockDim.x;
    for (; i < E; i += stride) {
        int d = dst[i];
        int pos = offs[d] + atomicAdd(&cursor[d], 1);
        csr_src[pos] = src[i];
    }
}

// ---------------- generic fp32 tiled GEMM with fused epilogue ----------------
// out[M][Nc] = op( concat(A1[M][K1], A2[M][K2]) @ W[K][Nc] )
// op: optional negate-A, +bias, relu, +addsrc

#define BM 64
#define BN 64
#define BK 16

__global__ __launch_bounds__(TPB) void k_gemm(
    const float* __restrict__ A1, int K1,
    const float* __restrict__ A2, int K2,
    const float* __restrict__ W,
    const float* __restrict__ bias,
    const float* __restrict__ addsrc,
    float* __restrict__ out,
    int M, int Nc, int negA, int doRelu)
{
    __shared__ float As[BK][BM + 4];
    __shared__ float Bs[BK][BN];
    const int tid = threadIdx.x;
    const int row0 = blockIdx.x * BM;
    const int K = K1 + K2;
    const int ty = tid >> 4, tx = tid & 15;
    float acc[4][4] = {{0.f}};

    for (int k0 = 0; k0 < K; k0 += BK) {
        // --- A tile: 64 rows x 16 cols, float4 per thread ---
        {
            int r = tid >> 2;
            int cq = (tid & 3) * 4;
            int row = row0 + r;
            int rowc = row < M ? row : M - 1;
            int c = k0 + cq;
            float4 v;
            if (c + 3 < K1) {
                v = *(const float4*)(A1 + (size_t)rowc * K1 + c);
            } else if (c >= K1 && c + 3 < K) {
                v = *(const float4*)(A2 + (size_t)rowc * K2 + (c - K1));
            } else {
                float t0 = 0.f, t1 = 0.f, t2 = 0.f, t3 = 0.f;
                int cc;
                cc = c + 0; if (cc < K1) t0 = A1[(size_t)rowc * K1 + cc]; else if (cc < K) t0 = A2[(size_t)rowc * K2 + cc - K1];
                cc = c + 1; if (cc < K1) t1 = A1[(size_t)rowc * K1 + cc]; else if (cc < K) t1 = A2[(size_t)rowc * K2 + cc - K1];
                cc = c + 2; if (cc < K1) t2 = A1[(size_t)rowc * K1 + cc]; else if (cc < K) t2 = A2[(size_t)rowc * K2 + cc - K1];
                cc = c + 3; if (cc < K1) t3 = A1[(size_t)rowc * K1 + cc]; else if (cc < K) t3 = A2[(size_t)rowc * K2 + cc - K1];
                v = make_float4(t0, t1, t2, t3);
            }
            if (negA) { v.x = -v.x; v.y = -v.y; v.z = -v.z; v.w = -v.w; }
            As[cq + 0][r] = v.x; As[cq + 1][r] = v.y; As[cq + 2][r] = v.z; As[cq + 3][r] = v.w;
        }
        // --- B tile: 16 rows x 64 cols ---
        {
            int r = tid >> 4;
            int cq = (tid & 15) * 4;
            int kk = k0 + r;
            float4 v = make_float4(0.f, 0.f, 0.f, 0.f);
            if (kk < K && cq + 3 < Nc) v = *(const float4*)(W + (size_t)kk * Nc + cq);
            Bs[r][cq + 0] = v.x; Bs[r][cq + 1] = v.y; Bs[r][cq + 2] = v.z; Bs[r][cq + 3] = v.w;
        }
        __syncthreads();
#pragma unroll
        for (int kk = 0; kk < BK; ++kk) {
            float a[4], b[4];
#pragma unroll
            for (int i = 0; i < 4; ++i) a[i] = As[kk][ty * 4 + i];
#pragma unroll
            for (int j = 0; j < 4; ++j) b[j] = Bs[kk][tx * 4 + j];
#pragma unroll
            for (int i = 0; i < 4; ++i)
#pragma unroll
                for (int j = 0; j < 4; ++j)
                    acc[i][j] = fmaf(a[i], b[j], acc[i][j]);
        }
        __syncthreads();
    }
#pragma unroll
    for (int i = 0; i < 4; ++i) {
        int row = row0 + ty * 4 + i;
        if (row >= M) continue;
#pragma unroll
        for (int j = 0; j < 4; ++j) {
            int col = tx * 4 + j;
            if (col >= Nc) continue;
            float v = acc[i][j];
            if (bias) v += bias[col];
            if (doRelu) v = fmaxf(v, 0.f);
            if (addsrc) v += addsrc[(size_t)row * Nc + col];
            out[(size_t)row * Nc + col] = v;
        }
    }
}

// ---------------- alpha: per-node attention dot products ----------------
// as_out[n][h] = sum_c h[n,h,c]*a_src[h,c] ; same for ad_out

__global__ __launch_bounds__(TPB) void k_alpha(const float* __restrict__ h,
                                               const float* __restrict__ a_s,
                                               const float* __restrict__ a_d,
                                               float* __restrict__ as_out,
                                               float* __restrict__ ad_out, int M) {
    int w = (blockIdx.x * blockDim.x + threadIdx.x) >> 6;
    int lane = threadIdx.x & 63;
    if (w >= M) return;
    float hv = h[(size_t)w * 64 + lane];
    float s = hv * a_s[lane];
    float d = hv * a_d[lane];
#pragma unroll
    for (int off = 16; off > 0; off >>= 1) {
        s += __shfl_xor(s, off);
        d += __shfl_xor(d, off);
    }
    if ((lane & 31) == 0) {
        int head = lane >> 5;
        as_out[(size_t)w * 2 + head] = s;
        ad_out[(size_t)w * 2 + head] = d;
    }
}

// ---------------- GAT aggregation: wave per dst node, lane = channel ----------------
// single-pass softmax (no max subtraction; logits are O(few)), fused bias+elu, optional LN

__global__ __launch_bounds__(TPB) void k_agg(const int* __restrict__ offs, const int* __restrict__ csr_src,
                                             const float* __restrict__ h,
                                             const float* __restrict__ as_,
                                             const float* __restrict__ ad_,
                                             const float* __restrict__ bias,
                                             const float* __restrict__ ln_g,
                                             const float* __restrict__ ln_b,
                                             float* __restrict__ out, int M, int do_ln) {
    int w = (blockIdx.x * blockDim.x + threadIdx.x) >> 6;
    int lane = threadIdx.x & 63;
    if (w >= M) return;
    int head = lane >> 5;
    float adv = ad_[(size_t)w * 2 + head];
    int beg = offs[w], end = offs[w + 1];
    float acc = 0.f, den = 0.f;
    for (int k = beg; k < end; ++k) {
        int s = csr_src[k];
        float e = as_[(size_t)s * 2 + head] + adv;
        e = e > 0.f ? e : 0.2f * e;
        float p = __expf(e);
        den += p;
        acc = fmaf(p, h[(size_t)s * 64 + lane], acc);
    }
    float o = acc / (den + 1e-16f) + bias[lane];
    o = o > 0.f ? o : expm1f(o);  // elu
    if (do_ln) {
        float mu = o;
#pragma unroll
        for (int off = 32; off > 0; off >>= 1) mu += __shfl_xor(mu, off);
        mu *= (1.f / 64.f);
        float dv = (o - mu) * (o - mu);
#pragma unroll
        for (int off = 32; off > 0; off >>= 1) dv += __shfl_xor(dv, off);
        dv *= (1.f / 64.f);
        o = (o - mu) * rsqrtf(dv + 1e-5f) * ln_g[lane] + ln_b[lane];
    }
    out[(size_t)w * 64 + lane] = o;
}

// ---------------- launcher ----------------

extern "C" void kernel_launch(void* const* d_in, const int* in_sizes, int n_in,
                              void* d_out, int out_size, void* d_ws, size_t ws_size,
                              hipStream_t stream) {
    const float* x      = (const float*)d_in[0];
    const float* eig    = (const float*)d_in[1];
    const int*   ei     = (const int*)d_in[2];
    const float* phi_w1 = (const float*)d_in[3];
    const float* phi_b1 = (const float*)d_in[4];
    const float* phi_w2 = (const float*)d_in[5];
    const float* phi_b2 = (const float*)d_in[6];
    const float* rho_w  = (const float*)d_in[7];
    const float* rho_b  = (const float*)d_in[8];
    const float* W0     = (const float*)d_in[9];
    const float* asrc0  = (const float*)d_in[10];
    const float* adst0  = (const float*)d_in[11];
    const float* b0     = (const float*)d_in[12];
    const float* W1     = (const float*)d_in[13];
    const float* asrc1  = (const float*)d_in[14];
    const float* adst1  = (const float*)d_in[15];
    const float* b1     = (const float*)d_in[16];
    const float* ln_g   = (const float*)d_in[17];
    const float* ln_b   = (const float*)d_in[18];

    const int N = in_sizes[0] / 128;
    const int E = in_sizes[2] / 2;
    const int* esrc = ei;
    const int* edst = ei + E;

    auto alignup = [](size_t v) { return (v + 255) & ~(size_t)255; };
    char* w = (char*)d_ws;
    int* counts = (int*)w; w += alignup((size_t)(N + 1) * 4);
    int* offs   = (int*)w; w += alignup((size_t)(N + 1) * 4);
    int* cursor = (int*)w; w += alignup((size_t)N * 4);
    int* bsum   = (int*)w; w += alignup(4096);
    int* csr    = (int*)w; w += alignup((size_t)E * 4);
    float* B1   = (float*)w; w += alignup((size_t)N * 64 * 4);
    float* PE   = (float*)w; w += alignup((size_t)N * 32 * 4);
    float* as0  = (float*)w; w += alignup((size_t)N * 2 * 4);
    float* ad0  = (float*)w; w += alignup((size_t)N * 2 * 4);
    float* B2   = (float*)d_out;  // [N,64] scratch; fully rewritten by the final kernel

    // ---- CSR build ----
    int gz = (N + TPB) / TPB;
    k_zero<<<gz, TPB, 0, stream>>>(counts, cursor, N);
    int ge = (E + TPB - 1) / TPB;
    k_count<<<ge, TPB, 0, stream>>>(edst, counts, E);
    int nb = (N + 1 + 1023) / 1024;
    k_scan1<<<nb, TPB, 0, stream>>>(counts, bsum, N + 1);
    k_scan2<<<1, 128, 0, stream>>>(bsum, nb);
    k_scan3<<<nb, TPB, 0, stream>>>(counts, bsum, offs, N + 1);
    k_scatter<<<ge, TPB, 0, stream>>>(esrc, edst, offs, cursor, csr, E);

    int gM = (N + BM - 1) / BM;
    // ---- SignNet ----
    // T1n = relu(-eig @ phi_w1 + b1) -> B1
    k_gemm<<<gM, TPB, 0, stream>>>(eig, 8, nullptr, 0, phi_w1, phi_b1, nullptr, B1, N, 64, 1, 1);
    // T2n = relu(B1 @ phi_w2 + b2) -> B2 (=d_out scratch)
    k_gemm<<<gM, TPB, 0, stream>>>(B1, 64, nullptr, 0, phi_w2, phi_b2, nullptr, B2, N, 64, 0, 1);
    // T1p = relu(eig @ phi_w1 + b1) -> B1
    k_gemm<<<gM, TPB, 0, stream>>>(eig, 8, nullptr, 0, phi_w1, phi_b1, nullptr, B1, N, 64, 0, 1);
    // S = relu(B1 @ phi_w2 + b2) + T2n -> B1 (in-place safe: block writes only its own rows)
    k_gemm<<<gM, TPB, 0, stream>>>(B1, 64, nullptr, 0, phi_w2, phi_b2, B2, B1, N, 64, 0, 1);
    // PE = S @ rho_w + rho_b -> PE
    k_gemm<<<gM, TPB, 0, stream>>>(B1, 64, nullptr, 0, rho_w, rho_b, nullptr, PE, N, 32, 0, 0);

    // ---- GAT layer 0 ----
    // h0 = [x | PE] @ W0 -> B1
    k_gemm<<<gM, TPB, 0, stream>>>(x, 128, PE, 32, W0, nullptr, nullptr, B1, N, 64, 0, 0);
    int ga = (N + 3) / 4;
    k_alpha<<<ga, TPB, 0, stream>>>(B1, asrc0, adst0, as0, ad0, N);
    // g0 -> B2 (=d_out scratch)
    k_agg<<<ga, TPB, 0, stream>>>(offs, csr, B1, as0, ad0, b0, nullptr, nullptr, B2, N, 0);

    // ---- GAT layer 1 ----
    // h1 = g0 @ W1 -> B1
    k_gemm<<<gM, TPB, 0, stream>>>(B2, 64, nullptr, 0, W1, nullptr, nullptr, B1, N, 64, 0, 0);
    k_alpha<<<ga, TPB, 0, stream>>>(B1, asrc1, adst1, as0, ad0, N);
    // final: aggregate + bias + elu + LayerNorm -> d_out
    k_agg<<<ga, TPB, 0, stream>>>(offs, csr, B1, as0, ad0, b1, ln_g, ln_b, (float*)d_out, N, 1);

    (void)n_in; (void)ws_size; (void)out_size;
}

// Round 3
// 445.840 us; speedup vs baseline: 1.5619x; 1.5619x over previous
//
#include <hip/hip_runtime.h>
#include <cstdint>
#include <cstddef>

#define TPB 256

__device__ __forceinline__ ushort f2b(float f) {
    union { float f; uint32_t u; } v; v.f = f;
    uint32_t r = (v.u + 0x7FFFu + ((v.u >> 16) & 1u)) >> 16;
    return (ushort)r;
}
__device__ __forceinline__ float b2f(ushort h) {
    union { uint32_t u; float f; } v; v.u = ((uint32_t)h) << 16;
    return v.f;
}

// ---------------- CSR build ----------------

__global__ __launch_bounds__(TPB) void k_zero(int* __restrict__ counts, int* __restrict__ cursor, int n) {
    int i = blockIdx.x * blockDim.x + threadIdx.x;
    int stride = gridDim.x * blockDim.x;
    for (; i <= n; i += stride) {
        counts[i] = 0;
        if (i < n) cursor[i] = 0;
    }
}

__global__ __launch_bounds__(TPB) void k_count(const int* __restrict__ dst, int* __restrict__ counts, int E) {
    int i = blockIdx.x * blockDim.x + threadIdx.x;
    int stride = gridDim.x * blockDim.x;
    for (; i < E; i += stride) atomicAdd(&counts[dst[i]], 1);
}

__global__ __launch_bounds__(TPB) void k_scan1(const int* __restrict__ counts, int* __restrict__ bsum, int total) {
    __shared__ int sh[TPB];
    int base = blockIdx.x * 1024;
    int s = 0;
#pragma unroll
    for (int j = 0; j < 4; ++j) {
        int idx = base + threadIdx.x * 4 + j;
        if (idx < total) s += counts[idx];
    }
    sh[threadIdx.x] = s;
    __syncthreads();
    for (int off = 128; off > 0; off >>= 1) {
        if (threadIdx.x < off) sh[threadIdx.x] += sh[threadIdx.x + off];
        __syncthreads();
    }
    if (threadIdx.x == 0) bsum[blockIdx.x] = sh[0];
}

__global__ void k_scan2(int* __restrict__ bsum, int nb) {
    __shared__ int sh[128];
    int t = threadIdx.x;
    int v = (t < nb) ? bsum[t] : 0;
    sh[t] = v;
    __syncthreads();
    for (int off = 1; off < 128; off <<= 1) {
        int u = 0;
        if (t >= off) u = sh[t - off];
        __syncthreads();
        sh[t] += u;
        __syncthreads();
    }
    if (t < nb) bsum[t] = sh[t] - v;  // exclusive
}

__global__ __launch_bounds__(TPB) void k_scan3(const int* __restrict__ counts, const int* __restrict__ bsum,
                                               int* __restrict__ offs, int total) {
    __shared__ int sh[TPB];
    int base = blockIdx.x * 1024;
    int v[4];
    int s = 0;
#pragma unroll
    for (int j = 0; j < 4; ++j) {
        int idx = base + threadIdx.x * 4 + j;
        v[j] = (idx < total) ? counts[idx] : 0;
        s += v[j];
    }
    sh[threadIdx.x] = s;
    __syncthreads();
    for (int off = 1; off < TPB; off <<= 1) {
        int t = 0;
        if (threadIdx.x >= off) t = sh[threadIdx.x - off];
        __syncthreads();
        sh[threadIdx.x] += t;
        __syncthreads();
    }
    int pre = bsum[blockIdx.x] + sh[threadIdx.x] - s;
#pragma unroll
    for (int j = 0; j < 4; ++j) {
        int idx = base + threadIdx.x * 4 + j;
        if (idx < total) { offs[idx] = pre; pre += v[j]; }
    }
}

__global__ __launch_bounds__(TPB) void k_scatter(const int* __restrict__ src, const int* __restrict__ dst,
                                                 const int* __restrict__ offs, int* __restrict__ cursor,
                                                 int* __restrict__ csr_src, int E) {
    int i = blockIdx.x * blockDim.x + threadIdx.x;
    int stride = gridDim.x * blockDim.x;
    for (; i < E; i += stride) {
        int d = dst[i];
        int pos = offs[d] + atomicAdd(&cursor[d], 1);
        csr_src[pos] = src[i];
    }
}

// ---------------- R = rho_w @ W0_pe ; cvec = rho_b @ W0_pe ----------------

__global__ __launch_bounds__(TPB) void k_rinit(const float* __restrict__ rho_w, const float* __restrict__ rho_b,
                                               const float* __restrict__ W0, float* __restrict__ R,
                                               float* __restrict__ cvec) {
    const float* Wpe = W0 + 128 * 64;  // rows 128..159 of W0
    int tid = threadIdx.x;
    for (int idx = tid; idx < 64 * 64; idx += TPB) {
        int r = idx >> 6, cc = idx & 63;
        float s = 0.f;
#pragma unroll
        for (int k = 0; k < 32; ++k) s = fmaf(rho_w[r * 32 + k], Wpe[k * 64 + cc], s);
        R[idx] = s;
    }
    if (tid < 64) {
        float s = 0.f;
#pragma unroll
        for (int k = 0; k < 32; ++k) s = fmaf(rho_b[k], Wpe[k * 64 + tid], s);
        cvec[tid] = s;
    }
}

// ---------------- phi1 dual: t = eig@w1 ; P=relu(t+b), Q=relu(-t+b) (bf16 out) ----------------

__global__ __launch_bounds__(TPB) void k_phi1(const float* __restrict__ eig, const float* __restrict__ w1,
                                              const float* __restrict__ b1,
                                              ushort* __restrict__ P, ushort* __restrict__ Q, int M) {
    __shared__ float ws[512];
    __shared__ float bs[64];
    for (int i = threadIdx.x; i < 512; i += TPB) ws[i] = w1[i];
    if (threadIdx.x < 64) bs[threadIdx.x] = b1[threadIdx.x];
    __syncthreads();
    int widx = threadIdx.x >> 6, lane = threadIdx.x & 63;
    for (int n = blockIdx.x * 4 + widx; n < M; n += gridDim.x * 4) {
        float ev = (lane < 8) ? eig[(size_t)n * 8 + lane] : 0.f;
        float t = 0.f;
#pragma unroll
        for (int k = 0; k < 8; ++k) t = fmaf(__shfl(ev, k), ws[k * 64 + lane], t);
        float bb = bs[lane];
        P[(size_t)n * 64 + lane] = f2b(fmaxf(t + bb, 0.f));
        Q[(size_t)n * 64 + lane] = f2b(fmaxf(bb - t, 0.f));
    }
}

// ---------------- phi2 dual: S = relu(P@W2+b2) + relu(Q@W2+b2)  (bf16 in/out, K=64) ----------------

__global__ __launch_bounds__(TPB) void k_phi2(const ushort* __restrict__ P, const ushort* __restrict__ Q,
                                              const float* __restrict__ W, const float* __restrict__ b,
                                              ushort* __restrict__ S, int M) {
    __shared__ float Ap[64][65];
    __shared__ float Aq[64][65];
    __shared__ float Ws[64][64];
    const int tid = threadIdx.x;
    const int row0 = blockIdx.x * 64;
    for (int i = tid; i < 1024; i += TPB) {
        float4 v = *(const float4*)(W + i * 4);
        Ws[0][i * 4 + 0] = v.x; Ws[0][i * 4 + 1] = v.y; Ws[0][i * 4 + 2] = v.z; Ws[0][i * 4 + 3] = v.w;
    }
    {
        int r = tid >> 2;
        int c0 = (tid & 3) * 16;
        int row = row0 + r; int rowc = row < M ? row : M - 1;
        const uint4* pp = (const uint4*)(P + (size_t)rowc * 64 + c0);
        const uint4* qq = (const uint4*)(Q + (size_t)rowc * 64 + c0);
#pragma unroll
        for (int half = 0; half < 2; ++half) {
            uint4 up = pp[half], uq = qq[half];
            const ushort* sp = (const ushort*)&up;
            const ushort* sq = (const ushort*)&uq;
#pragma unroll
            for (int j = 0; j < 8; ++j) {
                Ap[c0 + half * 8 + j][r] = b2f(sp[j]);
                Aq[c0 + half * 8 + j][r] = b2f(sq[j]);
            }
        }
    }
    __syncthreads();
    const int ty = tid >> 4, tx = tid & 15;
    float accp[4][4] = {{0.f}}, accq[4][4] = {{0.f}};
#pragma unroll 8
    for (int kk = 0; kk < 64; ++kk) {
        float ap[4], aq[4], bw[4];
#pragma unroll
        for (int i = 0; i < 4; ++i) { ap[i] = Ap[kk][ty * 4 + i]; aq[i] = Aq[kk][ty * 4 + i]; }
#pragma unroll
        for (int j = 0; j < 4; ++j) bw[j] = Ws[kk][tx * 4 + j];
#pragma unroll
        for (int i = 0; i < 4; ++i)
#pragma unroll
            for (int j = 0; j < 4; ++j) {
                accp[i][j] = fmaf(ap[i], bw[j], accp[i][j]);
                accq[i][j] = fmaf(aq[i], bw[j], accq[i][j]);
            }
    }
#pragma unroll
    for (int i = 0; i < 4; ++i) {
        int row = row0 + ty * 4 + i;
        if (row >= M) continue;
        ushort4 o;
        ushort* op = (ushort*)&o;
#pragma unroll
        for (int j = 0; j < 4; ++j) {
            int col = tx * 4 + j;
            float bb = b[col];
            float v = fmaxf(accp[i][j] + bb, 0.f) + fmaxf(accq[i][j] + bb, 0.f);
            op[j] = f2b(v);
        }
        *(ushort4*)(S + (size_t)row * 64 + tx * 4) = o;
    }
}

// ---------------- generic main GEMM: out_bf16 = [A1_f32(K1) | A2_bf16(K2)] @ [Wa;Wb] + bias ----------------

#define BM 64
#define BK 16

__global__ __launch_bounds__(TPB) void k_mm(const float* __restrict__ A1, int K1,
                                            const ushort* __restrict__ A2, int K2,
                                            const float* __restrict__ Wa, const float* __restrict__ Wb,
                                            const float* __restrict__ bias,
                                            ushort* __restrict__ out, int M) {
    __shared__ float As[BK][BM + 4];
    __shared__ float Bs[BK][64];
    const int tid = threadIdx.x;
    const int row0 = blockIdx.x * BM;
    const int K = K1 + K2;
    const int ty = tid >> 4, tx = tid & 15;
    float acc[4][4] = {{0.f}};

    for (int k0 = 0; k0 < K; k0 += BK) {
        {
            int r = tid >> 2;
            int cq = (tid & 3) * 4;
            int row = row0 + r;
            int rowc = row < M ? row : M - 1;
            int c = k0 + cq;
            float4 v;
            if (c < K1) {
                v = *(const float4*)(A1 + (size_t)rowc * K1 + c);
            } else {
                const ushort* p = A2 + (size_t)rowc * K2 + (c - K1);
                ushort4 u = *(const ushort4*)p;
                v = make_float4(b2f(u.x), b2f(u.y), b2f(u.z), b2f(u.w));
            }
            As[cq + 0][r] = v.x; As[cq + 1][r] = v.y; As[cq + 2][r] = v.z; As[cq + 3][r] = v.w;
        }
        {
            int rr = tid >> 4;
            int cq2 = (tid & 15) * 4;
            int kk = k0 + rr;
            const float* Wrow = (kk < K1) ? (Wa + (size_t)kk * 64) : (Wb + (size_t)(kk - K1) * 64);
            float4 wv = *(const float4*)(Wrow + cq2);
            Bs[rr][cq2 + 0] = wv.x; Bs[rr][cq2 + 1] = wv.y; Bs[rr][cq2 + 2] = wv.z; Bs[rr][cq2 + 3] = wv.w;
        }
        __syncthreads();
#pragma unroll
        for (int kk = 0; kk < BK; ++kk) {
            float a[4], bw[4];
#pragma unroll
            for (int i = 0; i < 4; ++i) a[i] = As[kk][ty * 4 + i];
#pragma unroll
            for (int j = 0; j < 4; ++j) bw[j] = Bs[kk][tx * 4 + j];
#pragma unroll
            for (int i = 0; i < 4; ++i)
#pragma unroll
                for (int j = 0; j < 4; ++j)
                    acc[i][j] = fmaf(a[i], bw[j], acc[i][j]);
        }
        __syncthreads();
    }
#pragma unroll
    for (int i = 0; i < 4; ++i) {
        int row = row0 + ty * 4 + i;
        if (row >= M) continue;
        ushort4 o;
        ushort* op = (ushort*)&o;
#pragma unroll
        for (int j = 0; j < 4; ++j) {
            int col = tx * 4 + j;
            float v = acc[i][j];
            if (bias) v += bias[col];
            op[j] = f2b(v);
        }
        *(ushort4*)(out + (size_t)row * 64 + tx * 4) = o;
    }
}

// ---------------- alpha: per-node attention dot products (bf16 h) ----------------

__global__ __launch_bounds__(TPB) void k_alpha(const ushort* __restrict__ hb,
                                               const float* __restrict__ a_s,
                                               const float* __restrict__ a_d,
                                               float2* __restrict__ as2,
                                               float2* __restrict__ ad2, int M) {
    int w = (blockIdx.x * blockDim.x + threadIdx.x) >> 6;
    int lane = threadIdx.x & 63;
    if (w >= M) return;
    float hv = b2f(hb[(size_t)w * 64 + lane]);
    float s = hv * a_s[lane];
    float d = hv * a_d[lane];
#pragma unroll
    for (int off = 16; off > 0; off >>= 1) {
        s += __shfl_xor(s, off);
        d += __shfl_xor(d, off);
    }
    float s0 = __shfl(s, 0), s1 = __shfl(s, 32);
    float d0 = __shfl(d, 0), d1 = __shfl(d, 32);
    if (lane == 0) {
        as2[w] = make_float2(s0, s1);
        ad2[w] = make_float2(d0, d1);
    }
}

// ---------------- GAT aggregation: wave per dst, lane = channel ----------------
// chunked coalesced csr+alpha loads, per-edge p precomputed in home lane,
// 4x unrolled gathers. NOTE: all __shfl executed by the FULL wave (no divergent
// shfl: ds_bpermute from an exec-masked-off source lane is undefined on CDNA),
// per-head value selected AFTER the shuffle.

template <int DO_LN>
__global__ __launch_bounds__(TPB) void k_agg(const int* __restrict__ offs, const int* __restrict__ csr_src,
                                             const ushort* __restrict__ hb,
                                             const float2* __restrict__ as2,
                                             const float2* __restrict__ ad2,
                                             const float* __restrict__ bias,
                                             const float* __restrict__ ln_g,
                                             const float* __restrict__ ln_b,
                                             float* __restrict__ out, int M) {
    int w = (blockIdx.x * blockDim.x + threadIdx.x) >> 6;
    int lane = threadIdx.x & 63;
    if (w >= M) return;
    int head = lane >> 5;
    float2 adv = ad2[w];
    int beg = offs[w], end = offs[w + 1];
    float acc = 0.f, den = 0.f;
    for (int base = beg; base < end; base += 64) {
        int nk = end - base;
        if (nk > 64) nk = 64;
        int sidx = csr_src[base + (lane < nk ? lane : 0)];
        float2 av = as2[sidx];
        float e0 = av.x + adv.x; e0 = e0 > 0.f ? e0 : 0.2f * e0;
        float e1 = av.y + adv.y; e1 = e1 > 0.f ? e1 : 0.2f * e1;
        float p0 = __expf(e0), p1 = __expf(e1);
        int j = 0;
        for (; j + 4 <= nk; j += 4) {
            int s0 = __shfl(sidx, j + 0), s1 = __shfl(sidx, j + 1);
            int s2 = __shfl(sidx, j + 2), s3 = __shfl(sidx, j + 3);
            ushort u0 = hb[(size_t)s0 * 64 + lane];
            ushort u1 = hb[(size_t)s1 * 64 + lane];
            ushort u2 = hb[(size_t)s2 * 64 + lane];
            ushort u3 = hb[(size_t)s3 * 64 + lane];
            float qa0 = __shfl(p0, j + 0), qa1 = __shfl(p1, j + 0);
            float qb0 = __shfl(p0, j + 1), qb1 = __shfl(p1, j + 1);
            float qc0 = __shfl(p0, j + 2), qc1 = __shfl(p1, j + 2);
            float qd0 = __shfl(p0, j + 3), qd1 = __shfl(p1, j + 3);
            float qa = head ? qa1 : qa0;
            float qb = head ? qb1 : qb0;
            float qc = head ? qc1 : qc0;
            float qd = head ? qd1 : qd0;
            den += qa + qb + qc + qd;
            acc = fmaf(qa, b2f(u0), acc);
            acc = fmaf(qb, b2f(u1), acc);
            acc = fmaf(qc, b2f(u2), acc);
            acc = fmaf(qd, b2f(u3), acc);
        }
        for (; j < nk; ++j) {
            int s = __shfl(sidx, j);
            float q0 = __shfl(p0, j), q1 = __shfl(p1, j);
            float q = head ? q1 : q0;
            den += q;
            acc = fmaf(q, b2f(hb[(size_t)s * 64 + lane]), acc);
        }
    }
    float o = acc / (den + 1e-16f) + bias[lane];
    o = o > 0.f ? o : expm1f(o);  // elu
    if (DO_LN) {
        float mu = o;
#pragma unroll
        for (int off = 32; off > 0; off >>= 1) mu += __shfl_xor(mu, off);
        mu *= (1.f / 64.f);
        float dv = (o - mu) * (o - mu);
#pragma unroll
        for (int off = 32; off > 0; off >>= 1) dv += __shfl_xor(dv, off);
        dv *= (1.f / 64.f);
        o = (o - mu) * rsqrtf(dv + 1e-5f) * ln_g[lane] + ln_b[lane];
    }
    out[(size_t)w * 64 + lane] = o;
}

// ---------------- launcher ----------------

extern "C" void kernel_launch(void* const* d_in, const int* in_sizes, int n_in,
                              void* d_out, int out_size, void* d_ws, size_t ws_size,
                              hipStream_t stream) {
    const float* x      = (const float*)d_in[0];
    const float* eig    = (const float*)d_in[1];
    const int*   ei     = (const int*)d_in[2];
    const float* phi_w1 = (const float*)d_in[3];
    const float* phi_b1 = (const float*)d_in[4];
    const float* phi_w2 = (const float*)d_in[5];
    const float* phi_b2 = (const float*)d_in[6];
    const float* rho_w  = (const float*)d_in[7];
    const float* rho_b  = (const float*)d_in[8];
    const float* W0     = (const float*)d_in[9];
    const float* asrc0  = (const float*)d_in[10];
    const float* adst0  = (const float*)d_in[11];
    const float* b0     = (const float*)d_in[12];
    const float* W1     = (const float*)d_in[13];
    const float* asrc1  = (const float*)d_in[14];
    const float* adst1  = (const float*)d_in[15];
    const float* b1     = (const float*)d_in[16];
    const float* ln_g   = (const float*)d_in[17];
    const float* ln_b   = (const float*)d_in[18];

    const int N = in_sizes[0] / 128;
    const int E = in_sizes[2] / 2;
    const int* esrc = ei;
    const int* edst = ei + E;

    auto alignup = [](size_t v) { return (v + 255) & ~(size_t)255; };
    char* w = (char*)d_ws;
    int* counts = (int*)w; w += alignup((size_t)(N + 1) * 4);
    int* offs   = (int*)w; w += alignup((size_t)(N + 1) * 4);
    int* cursor = (int*)w; w += alignup((size_t)N * 4);
    int* bsum   = (int*)w; w += alignup(4096);
    int* csr    = (int*)w; w += alignup((size_t)E * 4);
    ushort* Pb  = (ushort*)w; w += alignup((size_t)N * 64 * 2);  // phi1 pos; later S (phi2 out)
    ushort* Qb  = (ushort*)w; w += alignup((size_t)N * 64 * 2);  // phi1 neg
    ushort* hb  = (ushort*)w; w += alignup((size_t)N * 64 * 2);  // h0 / h1 bf16
    float2* as2 = (float2*)w; w += alignup((size_t)N * 8);
    float2* ad2 = (float2*)w; w += alignup((size_t)N * 8);
    float* R    = (float*)w; w += alignup(64 * 64 * 4);
    float* cvec = (float*)w; w += alignup(64 * 4);
    float* g0   = (float*)d_out;  // [N,64] fp32 scratch; fully rewritten by final agg

    // ---- CSR build ----
    int gz = (N + TPB) / TPB;
    k_zero<<<gz, TPB, 0, stream>>>(counts, cursor, N);
    int ge = (E + TPB - 1) / TPB;
    k_count<<<ge, TPB, 0, stream>>>(edst, counts, E);
    int nb = (N + 1 + 1023) / 1024;
    k_scan1<<<nb, TPB, 0, stream>>>(counts, bsum, N + 1);
    k_scan2<<<1, 128, 0, stream>>>(bsum, nb);
    k_scan3<<<nb, TPB, 0, stream>>>(counts, bsum, offs, N + 1);
    k_scatter<<<ge, TPB, 0, stream>>>(esrc, edst, offs, cursor, csr, E);

    k_rinit<<<1, TPB, 0, stream>>>(rho_w, rho_b, W0, R, cvec);

    int gM = (N + BM - 1) / BM;
    // ---- SignNet ----
    k_phi1<<<1024, TPB, 0, stream>>>(eig, phi_w1, phi_b1, Pb, Qb, N);
    k_phi2<<<gM, TPB, 0, stream>>>(Pb, Qb, phi_w2, phi_b2, Pb /* S in-place over P rows */, N);

    // ---- GAT layer 0: h0 = x@W0[:128] + S@R + cvec -> hb (bf16) ----
    k_mm<<<gM, TPB, 0, stream>>>(x, 128, Pb, 64, W0, R, cvec, hb, N);
    int ga = (N + 3) / 4;
    k_alpha<<<ga, TPB, 0, stream>>>(hb, asrc0, adst0, as2, ad2, N);
    k_agg<0><<<ga, TPB, 0, stream>>>(offs, csr, hb, as2, ad2, b0, nullptr, nullptr, g0, N);

    // ---- GAT layer 1: h1 = g0@W1 -> hb (bf16) ----
    k_mm<<<gM, TPB, 0, stream>>>(g0, 64, nullptr, 0, W1, nullptr, nullptr, hb, N);
    k_alpha<<<ga, TPB, 0, stream>>>(hb, asrc1, adst1, as2, ad2, N);
    k_agg<1><<<ga, TPB, 0, stream>>>(offs, csr, hb, as2, ad2, b1, ln_g, ln_b, (float*)d_out, N);

    (void)n_in; (void)ws_size; (void)out_size;
}

// Round 4
// 354.106 us; speedup vs baseline: 1.9665x; 1.2591x over previous
//
#include <hip/hip_runtime.h>
#include <cstdint>
#include <cstddef>

#define TPB 256

__device__ __forceinline__ ushort f2b(float f) {
    union { float f; uint32_t u; } v; v.f = f;
    uint32_t r = (v.u + 0x7FFFu + ((v.u >> 16) & 1u)) >> 16;
    return (ushort)r;
}
__device__ __forceinline__ float b2f(ushort h) {
    union { uint32_t u; float f; } v; v.u = ((uint32_t)h) << 16;
    return v.f;
}

// ---------------- CSR build (single-atomic: rank folded into count) ----------------

__global__ __launch_bounds__(TPB) void k_countrank(const int* __restrict__ dst, int* __restrict__ counts,
                                                   int* __restrict__ rank, int E) {
    int i = blockIdx.x * blockDim.x + threadIdx.x;
    if (i < E) rank[i] = atomicAdd(&counts[dst[i]], 1);
}

__global__ __launch_bounds__(TPB) void k_scan1(const int* __restrict__ counts, int* __restrict__ bsum, int total) {
    __shared__ int sh[TPB];
    int base = blockIdx.x * 1024;
    int s = 0;
#pragma unroll
    for (int j = 0; j < 4; ++j) {
        int idx = base + threadIdx.x * 4 + j;
        if (idx < total) s += counts[idx];
    }
    sh[threadIdx.x] = s;
    __syncthreads();
    for (int off = 128; off > 0; off >>= 1) {
        if (threadIdx.x < off) sh[threadIdx.x] += sh[threadIdx.x + off];
        __syncthreads();
    }
    if (threadIdx.x == 0) bsum[blockIdx.x] = sh[0];
}

__global__ void k_scan2(int* __restrict__ bsum, int nb) {
    __shared__ int sh[128];
    int t = threadIdx.x;
    int v = (t < nb) ? bsum[t] : 0;
    sh[t] = v;
    __syncthreads();
    for (int off = 1; off < 128; off <<= 1) {
        int u = 0;
        if (t >= off) u = sh[t - off];
        __syncthreads();
        sh[t] += u;
        __syncthreads();
    }
    if (t < nb) bsum[t] = sh[t] - v;  // exclusive
}

__global__ __launch_bounds__(TPB) void k_scan3(const int* __restrict__ counts, const int* __restrict__ bsum,
                                               int* __restrict__ offs, int total) {
    __shared__ int sh[TPB];
    int base = blockIdx.x * 1024;
    int v[4];
    int s = 0;
#pragma unroll
    for (int j = 0; j < 4; ++j) {
        int idx = base + threadIdx.x * 4 + j;
        v[j] = (idx < total) ? counts[idx] : 0;
        s += v[j];
    }
    sh[threadIdx.x] = s;
    __syncthreads();
    for (int off = 1; off < TPB; off <<= 1) {
        int t = 0;
        if (threadIdx.x >= off) t = sh[threadIdx.x - off];
        __syncthreads();
        sh[threadIdx.x] += t;
        __syncthreads();
    }
    int pre = bsum[blockIdx.x] + sh[threadIdx.x] - s;
#pragma unroll
    for (int j = 0; j < 4; ++j) {
        int idx = base + threadIdx.x * 4 + j;
        if (idx < total) { offs[idx] = pre; pre += v[j]; }
    }
}

__global__ __launch_bounds__(TPB) void k_scatter(const int* __restrict__ src, const int* __restrict__ dst,
                                                 const int* __restrict__ rank, const int* __restrict__ offs,
                                                 int* __restrict__ csr_src, int E) {
    int i = blockIdx.x * blockDim.x + threadIdx.x;
    if (i < E) csr_src[offs[dst[i]] + rank[i]] = src[i];
}

// ---------------- R = rho_w @ W0_pe ; cvec = rho_b @ W0_pe ----------------

__global__ __launch_bounds__(TPB) void k_rinit(const float* __restrict__ rho_w, const float* __restrict__ rho_b,
                                               const float* __restrict__ W0, float* __restrict__ R,
                                               float* __restrict__ cvec) {
    const float* Wpe = W0 + 128 * 64;  // rows 128..159 of W0
    int tid = threadIdx.x;
    for (int idx = tid; idx < 64 * 64; idx += TPB) {
        int r = idx >> 6, cc = idx & 63;
        float s = 0.f;
#pragma unroll
        for (int k = 0; k < 32; ++k) s = fmaf(rho_w[r * 32 + k], Wpe[k * 64 + cc], s);
        R[idx] = s;
    }
    if (tid < 64) {
        float s = 0.f;
#pragma unroll
        for (int k = 0; k < 32; ++k) s = fmaf(rho_b[k], Wpe[k * 64 + tid], s);
        cvec[tid] = s;
    }
}

// ---------------- fused SignNet: S = relu(relu(E@w1+b1)@w2+b2) + relu(relu(-E@w1+b1)@w2+b2) ----------------
// per block: 64 rows. P/Q tiles computed in LDS (no global round-trip), then dual-acc GEMM.

__global__ __launch_bounds__(TPB) void k_sign(const float* __restrict__ eig,
                                              const float* __restrict__ w1, const float* __restrict__ b1,
                                              const float* __restrict__ w2, const float* __restrict__ b2,
                                              ushort* __restrict__ S, int M) {
    __shared__ float eigS[64][9];
    __shared__ float w1s[512];
    __shared__ float b1s[64];
    __shared__ float Ap[64][65];
    __shared__ float Aq[64][65];
    __shared__ float Ws[64][64];
    const int tid = threadIdx.x;
    const int row0 = blockIdx.x * 64;

    // stage w1 [8][64], b1, w2 [64][64]
    for (int i = tid; i < 512; i += TPB) w1s[i] = w1[i];
    if (tid < 64) b1s[tid] = b1[tid];
    for (int i = tid; i < 1024; i += TPB) {
        float4 v = *(const float4*)(w2 + i * 4);
        Ws[0][i * 4 + 0] = v.x; Ws[0][i * 4 + 1] = v.y; Ws[0][i * 4 + 2] = v.z; Ws[0][i * 4 + 3] = v.w;
    }
    // stage eig rows (clamped)
    {
        int idx = tid * 2;
        int r = idx >> 3, c = idx & 7;
        int row = row0 + r; int rowc = row < M ? row : M - 1;
        float2 v = *(const float2*)(eig + (size_t)rowc * 8 + c);
        eigS[r][c] = v.x; eigS[r][c + 1] = v.y;
    }
    __syncthreads();

    // phi1 into LDS: thread (r = tid>>2, csub = tid&3) covers cols csub*16..csub*16+15
    {
        int r = tid >> 2, csub = tid & 3;
        float ev[8];
#pragma unroll
        for (int k = 0; k < 8; ++k) ev[k] = eigS[r][k];
#pragma unroll
        for (int c0 = 0; c0 < 16; ++c0) {
            int c = csub * 16 + c0;
            float t = 0.f;
#pragma unroll
            for (int k = 0; k < 8; ++k) t = fmaf(ev[k], w1s[k * 64 + c], t);
            float bb = b1s[c];
            Ap[c][r] = fmaxf(t + bb, 0.f);
            Aq[c][r] = fmaxf(bb - t, 0.f);
        }
    }
    __syncthreads();

    const int ty = tid >> 4, tx = tid & 15;
    float accp[4][4] = {{0.f}}, accq[4][4] = {{0.f}};
#pragma unroll 8
    for (int kk = 0; kk < 64; ++kk) {
        float ap[4], aq[4], bw[4];
#pragma unroll
        for (int i = 0; i < 4; ++i) { ap[i] = Ap[kk][ty * 4 + i]; aq[i] = Aq[kk][ty * 4 + i]; }
#pragma unroll
        for (int j = 0; j < 4; ++j) bw[j] = Ws[kk][tx * 4 + j];
#pragma unroll
        for (int i = 0; i < 4; ++i)
#pragma unroll
            for (int j = 0; j < 4; ++j) {
                accp[i][j] = fmaf(ap[i], bw[j], accp[i][j]);
                accq[i][j] = fmaf(aq[i], bw[j], accq[i][j]);
            }
    }
#pragma unroll
    for (int i = 0; i < 4; ++i) {
        int row = row0 + ty * 4 + i;
        if (row >= M) continue;
        ushort4 o;
        ushort* op = (ushort*)&o;
#pragma unroll
        for (int j = 0; j < 4; ++j) {
            int col = tx * 4 + j;
            float bb = b2[col];
            float v = fmaxf(accp[i][j] + bb, 0.f) + fmaxf(accq[i][j] + bb, 0.f);
            op[j] = f2b(v);
        }
        *(ushort4*)(S + (size_t)row * 64 + tx * 4) = o;
    }
}

// ---------------- main GEMM + fused alpha dot products ----------------
// out_bf16 = [A1_f32(K1) | A2_bf16(K2)] @ [Wa;Wb] + bias ; as2/ad2 per-row attention dots

#define BM 64
#define BK 16

__global__ __launch_bounds__(TPB) void k_mm(const float* __restrict__ A1, int K1,
                                            const ushort* __restrict__ A2, int K2,
                                            const float* __restrict__ Wa, const float* __restrict__ Wb,
                                            const float* __restrict__ bias,
                                            const float* __restrict__ a_s, const float* __restrict__ a_d,
                                            float2* __restrict__ as2, float2* __restrict__ ad2,
                                            ushort* __restrict__ out, int M) {
    __shared__ float As[BK][BM + 4];
    __shared__ float Bs[BK][64];
    const int tid = threadIdx.x;
    const int row0 = blockIdx.x * BM;
    const int K = K1 + K2;
    const int ty = tid >> 4, tx = tid & 15;
    float acc[4][4] = {{0.f}};

    for (int k0 = 0; k0 < K; k0 += BK) {
        {
            int r = tid >> 2;
            int cq = (tid & 3) * 4;
            int row = row0 + r;
            int rowc = row < M ? row : M - 1;
            int c = k0 + cq;
            float4 v;
            if (c < K1) {
                v = *(const float4*)(A1 + (size_t)rowc * K1 + c);
            } else {
                const ushort* p = A2 + (size_t)rowc * K2 + (c - K1);
                ushort4 u = *(const ushort4*)p;
                v = make_float4(b2f(u.x), b2f(u.y), b2f(u.z), b2f(u.w));
            }
            As[cq + 0][r] = v.x; As[cq + 1][r] = v.y; As[cq + 2][r] = v.z; As[cq + 3][r] = v.w;
        }
        {
            int rr = tid >> 4;
            int cq2 = (tid & 15) * 4;
            int kk = k0 + rr;
            const float* Wrow = (kk < K1) ? (Wa + (size_t)kk * 64) : (Wb + (size_t)(kk - K1) * 64);
            float4 wv = *(const float4*)(Wrow + cq2);
            Bs[rr][cq2 + 0] = wv.x; Bs[rr][cq2 + 1] = wv.y; Bs[rr][cq2 + 2] = wv.z; Bs[rr][cq2 + 3] = wv.w;
        }
        __syncthreads();
#pragma unroll
        for (int kk = 0; kk < BK; ++kk) {
            float a[4], bw[4];
#pragma unroll
            for (int i = 0; i < 4; ++i) a[i] = As[kk][ty * 4 + i];
#pragma unroll
            for (int j = 0; j < 4; ++j) bw[j] = Bs[kk][tx * 4 + j];
#pragma unroll
            for (int i = 0; i < 4; ++i)
#pragma unroll
                for (int j = 0; j < 4; ++j)
                    acc[i][j] = fmaf(a[i], bw[j], acc[i][j]);
        }
        __syncthreads();
    }

    // epilogue: finalize values, fused alpha partials
    float s_acc[4] = {0.f, 0.f, 0.f, 0.f}, d_acc[4] = {0.f, 0.f, 0.f, 0.f};
#pragma unroll
    for (int i = 0; i < 4; ++i) {
#pragma unroll
        for (int j = 0; j < 4; ++j) {
            int col = tx * 4 + j;
            float v = acc[i][j];
            if (bias) v += bias[col];
            acc[i][j] = v;
            s_acc[i] = fmaf(v, a_s[col], s_acc[i]);
            d_acc[i] = fmaf(v, a_d[col], d_acc[i]);
        }
    }
    // reduce across the 16-lane row group, heads kept separate (tx0-7 head0, tx8-15 head1).
    // full-wave shuffles (no divergence); only stores are guarded.
#pragma unroll
    for (int m = 1; m <= 4; m <<= 1) {
#pragma unroll
        for (int i = 0; i < 4; ++i) {
            s_acc[i] += __shfl_xor(s_acc[i], m);
            d_acc[i] += __shfl_xor(d_acc[i], m);
        }
    }
    float s_oth[4], d_oth[4];
#pragma unroll
    for (int i = 0; i < 4; ++i) {
        s_oth[i] = __shfl_xor(s_acc[i], 8);
        d_oth[i] = __shfl_xor(d_acc[i], 8);
    }
#pragma unroll
    for (int i = 0; i < 4; ++i) {
        int row = row0 + ty * 4 + i;
        if (row >= M) continue;
        ushort4 o;
        ushort* op = (ushort*)&o;
#pragma unroll
        for (int j = 0; j < 4; ++j) op[j] = f2b(acc[i][j]);
        *(ushort4*)(out + (size_t)row * 64 + tx * 4) = o;
        if (tx == 0) {
            as2[row] = make_float2(s_acc[i], s_oth[i]);
            ad2[row] = make_float2(d_acc[i], d_oth[i]);
        }
    }
}

// ---------------- GAT aggregation: wave per dst, lane = channel ----------------

template <int DO_LN>
__global__ __launch_bounds__(TPB) void k_agg(const int* __restrict__ offs, const int* __restrict__ csr_src,
                                             const ushort* __restrict__ hb,
                                             const float2* __restrict__ as2,
                                             const float2* __restrict__ ad2,
                                             const float* __restrict__ bias,
                                             const float* __restrict__ ln_g,
                                             const float* __restrict__ ln_b,
                                             float* __restrict__ out, int M) {
    int w = (blockIdx.x * blockDim.x + threadIdx.x) >> 6;
    int lane = threadIdx.x & 63;
    if (w >= M) return;
    int head = lane >> 5;
    float2 adv = ad2[w];
    int beg = offs[w], end = offs[w + 1];
    float acc = 0.f, den = 0.f;
    for (int base = beg; base < end; base += 64) {
        int nk = end - base;
        if (nk > 64) nk = 64;
        int sidx = csr_src[base + (lane < nk ? lane : 0)];
        float2 av = as2[sidx];
        float e0 = av.x + adv.x; e0 = e0 > 0.f ? e0 : 0.2f * e0;
        float e1 = av.y + adv.y; e1 = e1 > 0.f ? e1 : 0.2f * e1;
        float p0 = __expf(e0), p1 = __expf(e1);
        int j = 0;
        for (; j + 4 <= nk; j += 4) {
            int s0 = __shfl(sidx, j + 0), s1 = __shfl(sidx, j + 1);
            int s2 = __shfl(sidx, j + 2), s3 = __shfl(sidx, j + 3);
            ushort u0 = hb[(size_t)s0 * 64 + lane];
            ushort u1 = hb[(size_t)s1 * 64 + lane];
            ushort u2 = hb[(size_t)s2 * 64 + lane];
            ushort u3 = hb[(size_t)s3 * 64 + lane];
            float qa0 = __shfl(p0, j + 0), qa1 = __shfl(p1, j + 0);
            float qb0 = __shfl(p0, j + 1), qb1 = __shfl(p1, j + 1);
            float qc0 = __shfl(p0, j + 2), qc1 = __shfl(p1, j + 2);
            float qd0 = __shfl(p0, j + 3), qd1 = __shfl(p1, j + 3);
            float qa = head ? qa1 : qa0;
            float qb = head ? qb1 : qb0;
            float qc = head ? qc1 : qc0;
            float qd = head ? qd1 : qd0;
            den += qa + qb + qc + qd;
            acc = fmaf(qa, b2f(u0), acc);
            acc = fmaf(qb, b2f(u1), acc);
            acc = fmaf(qc, b2f(u2), acc);
            acc = fmaf(qd, b2f(u3), acc);
        }
        for (; j < nk; ++j) {
            int s = __shfl(sidx, j);
            float q0 = __shfl(p0, j), q1 = __shfl(p1, j);
            float q = head ? q1 : q0;
            den += q;
            acc = fmaf(q, b2f(hb[(size_t)s * 64 + lane]), acc);
        }
    }
    float o = acc / (den + 1e-16f) + bias[lane];
    o = o > 0.f ? o : expm1f(o);  // elu
    if (DO_LN) {
        float mu = o;
#pragma unroll
        for (int off = 32; off > 0; off >>= 1) mu += __shfl_xor(mu, off);
        mu *= (1.f / 64.f);
        float dv = (o - mu) * (o - mu);
#pragma unroll
        for (int off = 32; off > 0; off >>= 1) dv += __shfl_xor(dv, off);
        dv *= (1.f / 64.f);
        o = (o - mu) * rsqrtf(dv + 1e-5f) * ln_g[lane] + ln_b[lane];
    }
    out[(size_t)w * 64 + lane] = o;
}

// ---------------- launcher ----------------

extern "C" void kernel_launch(void* const* d_in, const int* in_sizes, int n_in,
                              void* d_out, int out_size, void* d_ws, size_t ws_size,
                              hipStream_t stream) {
    const float* x      = (const float*)d_in[0];
    const float* eig    = (const float*)d_in[1];
    const int*   ei     = (const int*)d_in[2];
    const float* phi_w1 = (const float*)d_in[3];
    const float* phi_b1 = (const float*)d_in[4];
    const float* phi_w2 = (const float*)d_in[5];
    const float* phi_b2 = (const float*)d_in[6];
    const float* rho_w  = (const float*)d_in[7];
    const float* rho_b  = (const float*)d_in[8];
    const float* W0     = (const float*)d_in[9];
    const float* asrc0  = (const float*)d_in[10];
    const float* adst0  = (const float*)d_in[11];
    const float* b0     = (const float*)d_in[12];
    const float* W1     = (const float*)d_in[13];
    const float* asrc1  = (const float*)d_in[14];
    const float* adst1  = (const float*)d_in[15];
    const float* b1     = (const float*)d_in[16];
    const float* ln_g   = (const float*)d_in[17];
    const float* ln_b   = (const float*)d_in[18];

    const int N = in_sizes[0] / 128;
    const int E = in_sizes[2] / 2;
    const int* esrc = ei;
    const int* edst = ei + E;

    auto alignup = [](size_t v) { return (v + 255) & ~(size_t)255; };
    char* w = (char*)d_ws;
    int* counts = (int*)w; w += alignup((size_t)(N + 1) * 4);
    int* offs   = (int*)w; w += alignup((size_t)(N + 1) * 4);
    int* rank   = (int*)w; w += alignup((size_t)E * 4);
    int* bsum   = (int*)w; w += alignup(4096);
    int* csr    = (int*)w; w += alignup((size_t)E * 4);
    ushort* Sb  = (ushort*)w; w += alignup((size_t)N * 64 * 2);  // SignNet output (bf16)
    ushort* hb  = (ushort*)w; w += alignup((size_t)N * 64 * 2);  // h0 / h1 bf16
    float2* as2 = (float2*)w; w += alignup((size_t)N * 8);
    float2* ad2 = (float2*)w; w += alignup((size_t)N * 8);
    float* R    = (float*)w; w += alignup(64 * 64 * 4);
    float* cvec = (float*)w; w += alignup(64 * 4);
    float* g0   = (float*)d_out;  // [N,64] fp32 scratch; fully rewritten by final agg

    // ---- CSR build ----
    hipMemsetAsync(counts, 0, (size_t)(N + 1) * 4, stream);
    int ge = (E + TPB - 1) / TPB;
    k_countrank<<<ge, TPB, 0, stream>>>(edst, counts, rank, E);
    int nb = (N + 1 + 1023) / 1024;
    k_scan1<<<nb, TPB, 0, stream>>>(counts, bsum, N + 1);
    k_scan2<<<1, 128, 0, stream>>>(bsum, nb);
    k_scan3<<<nb, TPB, 0, stream>>>(counts, bsum, offs, N + 1);
    k_scatter<<<ge, TPB, 0, stream>>>(esrc, edst, rank, offs, csr, E);

    k_rinit<<<1, TPB, 0, stream>>>(rho_w, rho_b, W0, R, cvec);

    int gM = (N + BM - 1) / BM;
    // ---- SignNet (fused phi1+phi2) ----
    k_sign<<<gM, TPB, 0, stream>>>(eig, phi_w1, phi_b1, phi_w2, phi_b2, Sb, N);

    // ---- GAT layer 0: h0 = x@W0[:128] + S@R + cvec -> hb (bf16), fused alpha ----
    k_mm<<<gM, TPB, 0, stream>>>(x, 128, Sb, 64, W0, R, cvec, asrc0, adst0, as2, ad2, hb, N);
    int ga = (N + 3) / 4;
    k_agg<0><<<ga, TPB, 0, stream>>>(offs, csr, hb, as2, ad2, b0, nullptr, nullptr, g0, N);

    // ---- GAT layer 1: h1 = g0@W1 -> hb (bf16), fused alpha ----
    k_mm<<<gM, TPB, 0, stream>>>(g0, 64, nullptr, 0, W1, nullptr, nullptr, asrc1, adst1, as2, ad2, hb, N);
    k_agg<1><<<ga, TPB, 0, stream>>>(offs, csr, hb, as2, ad2, b1, ln_g, ln_b, (float*)d_out, N);

    (void)n_in; (void)ws_size; (void)out_size;
}